// Round 4
// baseline (160.269 us; speedup 1.0000x reference)
//
#include <hip/hip_runtime.h>

typedef __bf16 bf16;
typedef bf16 bf16x8 __attribute__((ext_vector_type(8)));
typedef bf16 bf16x4 __attribute__((ext_vector_type(4)));
typedef bf16 bf16x2 __attribute__((ext_vector_type(2)));
typedef float f32x4 __attribute__((ext_vector_type(4)));

#define SEQ 4096
#define SQQ 1024
#define NH  6
#define HD  64

#define MFMA16 __builtin_amdgcn_mfma_f32_16x16x32_bf16

typedef const __attribute__((address_space(1))) void gvoid_t;
typedef __attribute__((address_space(3))) void svoid_t;

__device__ __forceinline__ void gload16(const bf16* g, bf16* l) {
  __builtin_amdgcn_global_load_lds((gvoid_t*)g, (svoid_t*)l, 16, 0, 0);
}

__device__ __forceinline__ int pk2(float a, float b) {
  union { bf16x2 h; int u; } c;
  c.h[0] = (bf16)a; c.h[1] = (bf16)b;
  return c.u;
}

// -------------------------------------------------------------------------
// K0: prep (R11: LDS-tiled COALESCED transposes).
//   blocks [0,216):    Wq [192][1152] -> Wqt bf16 [1152][192], 32x32 tiles
//   blocks [216,360):  Wp [384][384]  -> Wpt bf16 [384][384],  32x32 tiles
//   blocks [360,1896): X f32 -> Xb bf16 (vec8, coalesced)
// -------------------------------------------------------------------------
__global__ __launch_bounds__(256) void k_prep(
    const float* __restrict__ X, const float* __restrict__ Wq,
    const float* __restrict__ Wp,
    bf16* __restrict__ Xb, bf16* __restrict__ Wqt, bf16* __restrict__ Wpt)
{
  const int bid = blockIdx.x, tid = threadIdx.x;
  if (bid < 360) {
    __shared__ float tile[32][33];
    const float* src; bf16* dst; int k0, n0, sld, dld;
    if (bid < 216) {                   // Wq: k-rows 192, n-cols 1152
      int bn = bid % 36, bk = bid / 36;
      n0 = bn * 32; k0 = bk * 32;
      src = Wq; dst = Wqt; sld = 1152; dld = 192;
    } else {                           // Wp: 384 x 384
      int j = bid - 216;
      int bn = j % 12, bk = j / 12;
      n0 = bn * 32; k0 = bk * 32;
      src = Wp; dst = Wpt; sld = 384; dld = 384;
    }
    int c = tid & 31, r4 = tid >> 5;   // load: coalesced along n
#pragma unroll
    for (int i = 0; i < 4; ++i)
      tile[r4 * 4 + i][c] = src[(size_t)(k0 + r4 * 4 + i) * sld + n0 + c];
    __syncthreads();
    int r = tid & 31, c4 = tid >> 5;   // store: coalesced along k
#pragma unroll
    for (int i = 0; i < 4; ++i)
      dst[(size_t)(n0 + c4 * 4 + i) * dld + k0 + r] = (bf16)tile[r][c4 * 4 + i];
  } else {
    int v = (bid - 360) * 256 + tid;   // 393216 vec8 chunks
    f32x4 x0 = *(const f32x4*)&X[(size_t)v * 8];
    f32x4 x1 = *(const f32x4*)&X[(size_t)v * 8 + 4];
    bf16x8 h;
#pragma unroll
    for (int e = 0; e < 4; ++e) { h[e] = (bf16)x0[e]; h[4 + e] = (bf16)x1[e]; }
    *(bf16x8*)&Xb[(size_t)v * 8] = h;
  }
}

// -------------------------------------------------------------------------
// K1: QKV GEMM — R13 (proven): cooperative LDS staging, global_load_lds
// double-buffered K-chunks, XOR pre-swizzled source + swizzled ds_read_b128.
// Qs (Q-pool buffer) overlays buf0 behind an extra barrier.
// -------------------------------------------------------------------------
__global__ __launch_bounds__(256) void k_qkv(
    const bf16* __restrict__ Xb, const bf16* __restrict__ Wt,
    const float* __restrict__ bias,
    bf16* __restrict__ Kb, bf16* __restrict__ Vt, bf16* __restrict__ Qp)
{
  // SB[buf][ A[128][64] | B[128][64] ]  = 2 x 32KB = 64KB
  __shared__ __attribute__((aligned(16))) bf16 SB[2][2 * 128 * 64];
  const int tid = threadIdx.x;
  const int w = tid >> 6, lane = tid & 63, quad = lane >> 4, l16 = lane & 15;
  const int wm = w & 1, wn = w >> 1;
  const int m0 = blockIdx.x * 128, n0 = blockIdx.y * 128;
  const int c3 = n0 / 384, nb = n0 - c3 * 384, b = m0 >> 12;

  const int sr = lane >> 3;            // 0..7  (row within 8-row stripe)
  const int sc = (lane & 7) ^ sr;      // pre-swizzled source granule

  // staging: waves 0,1 -> A rows [w*64, w*64+64); waves 2,3 -> B rows
  const bf16* gsrc;
  bf16* ldst;
  if (w < 2) {
    gsrc = Xb + (size_t)(m0 + w * 64 + sr) * 192 + sc * 8;
    ldst = &SB[0][w * 4096];
  } else {
    gsrc = Wt + (size_t)(n0 + (w - 2) * 64 + sr) * 192 + sc * 8;
    ldst = &SB[0][8192 + (w - 2) * 4096];
  }
  const int bufstep = 2 * 128 * 64;    // elems between buffers

  // prologue: stage chunk 0 into buf 0 (8 issues/wave, 16B each)
#pragma unroll
  for (int i = 0; i < 8; ++i)
    gload16(gsrc + i * 1536, ldst + i * 512);

  // swizzled read offsets (bytes within a 128B row)
  const int sw0 = ((quad ^ (l16 & 7)) * 16);
  const int sw1 = (((4 + quad) ^ (l16 & 7)) * 16);

  f32x4 acc[4][4] = {};

  for (int kc = 0; kc < 3; ++kc) {
    const int p = kc & 1;
    __asm__ volatile("s_waitcnt vmcnt(0)" ::: "memory");
    __syncthreads();
    if (kc < 2) {
      const bf16* g2 = gsrc + (kc + 1) * 64;
      bf16* d2 = ldst + (p ^ 1) * bufstep;
#pragma unroll
      for (int i = 0; i < 8; ++i)
        gload16(g2 + i * 1536, d2 + i * 512);
    }
    const char* Ab = (const char*)&SB[p][0];
    const char* Bb = (const char*)&SB[p][8192];
#pragma unroll
    for (int kk = 0; kk < 2; ++kk) {
      const int swo = kk ? sw1 : sw0;
      bf16x8 af[4], bw[4];
#pragma unroll
      for (int t = 0; t < 4; ++t) {
        af[t] = *(const bf16x8*)(Ab + (wm * 64 + t * 16 + l16) * 128 + swo);
        bw[t] = *(const bf16x8*)(Bb + (wn * 64 + t * 16 + l16) * 128 + swo);
      }
      if (c3 == 2) {
#pragma unroll
        for (int mt = 0; mt < 4; ++mt)
#pragma unroll
          for (int nt = 0; nt < 4; ++nt)
            acc[mt][nt] = MFMA16(af[mt], bw[nt], acc[mt][nt], 0, 0, 0);
      } else {
#pragma unroll
        for (int mt = 0; mt < 4; ++mt)
#pragma unroll
          for (int nt = 0; nt < 4; ++nt)
            acc[mt][nt] = MFMA16(bw[nt], af[mt], acc[mt][nt], 0, 0, 0);
      }
    }
  }

  if (c3 == 2) {
    float bn[4];
#pragma unroll
    for (int nt = 0; nt < 4; ++nt) bn[nt] = bias[n0 + wn * 64 + nt * 16 + l16];
#pragma unroll
    for (int mt = 0; mt < 4; ++mt) {
      int sb = (m0 & 4095) + wm * 64 + mt * 16 + quad * 4;
#pragma unroll
      for (int nt = 0; nt < 4; ++nt) {
        int dcol = nb + wn * 64 + nt * 16 + l16;
        int h = dcol >> 6, dd = dcol & 63;
        bf16x4 pv;
#pragma unroll
        for (int r = 0; r < 4; ++r) pv[r] = (bf16)(acc[mt][nt][r] + bn[nt]);
        *(bf16x4*)&Vt[((size_t)(b * NH + h) * HD + dd) * SEQ + sb] = pv;
      }
    }
  } else if (c3 == 1) {
    f32x4 bv[4];
#pragma unroll
    for (int nt = 0; nt < 4; ++nt)
      bv[nt] = *(const f32x4*)&bias[n0 + wn * 64 + nt * 16 + quad * 4];
#pragma unroll
    for (int mt = 0; mt < 4; ++mt) {
      int s = (m0 & 4095) + wm * 64 + mt * 16 + l16;
#pragma unroll
      for (int nt = 0; nt < 4; ++nt) {
        int ncol = nb + wn * 64 + nt * 16 + quad * 4;
        int h = ncol >> 6, dd = ncol & 63;
        bf16x4 pv;
#pragma unroll
        for (int r = 0; r < 4; ++r) pv[r] = (bf16)(acc[mt][nt][r] + bv[nt][r]);
        *(bf16x4*)&Kb[((size_t)(b * NH + h) * SEQ + s) * HD + dd] = pv;
      }
    }
  } else {
    bf16* Qs = &SB[0][0];              // overlay (17408 elems <= 32768)
    f32x4 bv[4];
#pragma unroll
    for (int nt = 0; nt < 4; ++nt)
      bv[nt] = *(const f32x4*)&bias[n0 + wn * 64 + nt * 16 + quad * 4];
    __syncthreads();                   // buf0 was read by the kc=2 compute
#pragma unroll
    for (int mt = 0; mt < 4; ++mt) {
      int ml = wm * 64 + mt * 16 + l16;
#pragma unroll
      for (int nt = 0; nt < 4; ++nt) {
        int ncl = wn * 64 + nt * 16 + quad * 4;
        bf16x4 pv;
#pragma unroll
        for (int r = 0; r < 4; ++r) pv[r] = (bf16)(acc[mt][nt][r] + bv[nt][r]);
        *(bf16x4*)&Qs[ml * 136 + ncl] = pv;
      }
    }
    __syncthreads();
    const int wq = tid >> 3, cg = tid & 7;
    const int hq = (m0 & 4095) >> 7;
#pragma unroll
    for (int j8 = 0; j8 < 2; ++j8) {
      int co = cg * 16 + j8 * 8;
      bf16x8 q0 = *(const bf16x8*)&Qs[(2 * wq)     * 136 + co];
      bf16x8 q1 = *(const bf16x8*)&Qs[(2 * wq + 1) * 136 + co];
      bf16x8 q2 = *(const bf16x8*)&Qs[(64 + 2 * wq)     * 136 + co];
      bf16x8 q3 = *(const bf16x8*)&Qs[(64 + 2 * wq + 1) * 136 + co];
      bf16x8 o;
#pragma unroll
      for (int e = 0; e < 8; ++e) {
        float mx = fmaxf(fmaxf((float)q0[e], (float)q1[e]),
                         fmaxf((float)q2[e], (float)q3[e]));
        o[e] = (bf16)(mx * 0.180336880111f);   // 0.125 * log2(e)
      }
      int gc = nb + co;
      int h = gc >> 6, d0 = gc & 63;
      *(bf16x8*)&Qp[((size_t)(b * NH + h) * SQQ + hq * 32 + wq) * HD + d0] = o;
    }
  }
}

// -------------------------------------------------------------------------
// K3: attention — R15: R6 structure, but the P round-trip through LDS is
// replaced by an in-register 4-lane exchange (32 __shfl + 16 cndmask/iter).
// Derivation (verified on lanes 37, 17): QK^T leaves lane (quad',l16) with
// P[kpos=nt*16+quad'*4+r][q=qt*16+l16]; PV's B-fragment needs
// P[q=j*16+l16][kpos=ck*32+quad*8+e] at lane (quad,l16). Source lane =
// (quad&1)*32 + l16 (+16 for e>=4), source set nt = 2*ck + (quad>>1),
// reg r = e&3 — same l16 always, so pure quad-group shuffle.
// Deletes Pq (LDS 49152 -> 32768 => 4-5 blocks/CU vs 3), deletes the
// mid-iteration lgkmcnt(0) drain, deletes P bank conflicts.
// Grid (24, 8, 4), 256 thr. No setprio (R14 evidence: null/negative here).
// -------------------------------------------------------------------------
__global__ __launch_bounds__(256) void k_attn(
    const bf16* __restrict__ Qp, const bf16* __restrict__ Kb,
    const bf16* __restrict__ Vt, bf16* __restrict__ Op, float* __restrict__ lp)
{
  __shared__ __attribute__((aligned(16))) bf16 KVs0[2][64 * 64];  // K [kpos][d^]
  __shared__ __attribute__((aligned(16))) bf16 KVs1[2][64 * 64];  // V^T [d][kpos^]

  const int tid = threadIdx.x;
  const int w = tid >> 6, lane = tid & 63, quad = lane >> 4, l16 = lane & 15;
  const int bh = blockIdx.x, qb = blockIdx.y, ks = blockIdx.z;
  const int q0 = qb * 128 + w * 32;

  const bf16* Qg = Qp + (size_t)bh * SQQ * HD;
  const bf16* Kg = Kb + (size_t)bh * SEQ * HD;
  const bf16* Vg = Vt + (size_t)bh * HD * SEQ;

  bf16x8 qf[2][2];
#pragma unroll
  for (int qt = 0; qt < 2; ++qt)
#pragma unroll
    for (int dk = 0; dk < 2; ++dk)
      qf[qt][dk] = *(const bf16x8*)&Qg[(size_t)(q0 + qt * 16 + l16) * HD + dk * 32 + quad * 8];

  const int swz = l16 & 7;
  const int sw0 = ((quad ^ swz) * 16);
  const int sw1 = (((quad + 4) ^ swz) * 16);
  const int sr = lane >> 3;          // 0..7
  const int sc = (lane & 7) ^ sr;    // XOR-permuted source chunk

  const int hi = quad >> 1;                    // 0: nt=2ck, 1: nt=2ck+1
  const int shA = (quad & 1) * 32 + l16;       // source lane (e 0..3)
  const int shB = shA + 16;                    // source lane (e 4..7)

  const bf16* src;
  bf16 *dstA, *dstB;
  size_t rstride, step;
  if (w < 2) {
    src = Kg + (size_t)(ks * 1024 + w * 32 + sr) * HD + sc * 8;
    dstA = &KVs0[0][(w * 32) * 64];
    dstB = &KVs0[1][(w * 32) * 64];
    rstride = 8 * HD;  step = 64 * HD;
  } else {
    src = Vg + (size_t)((w - 2) * 32 + sr) * SEQ + ks * 1024 + sc * 8;
    dstA = &KVs1[0][((w - 2) * 32) * 64];
    dstB = &KVs1[1][((w - 2) * 32) * 64];
    rstride = 8 * SEQ; step = 64;
  }

#pragma unroll
  for (int c = 0; c < 4; ++c) gload16(src + c * rstride, dstA + c * 8 * 64);

  f32x4 lac[2] = {};
  f32x4 accO[4][2] = {};

  for (int it = 0; it < 16; ++it) {
    const int p = it & 1;
    __asm__ volatile("s_waitcnt vmcnt(0)" ::: "memory");
    __syncthreads();
    if (it < 15) {
      const bf16* s2 = src + (size_t)(it + 1) * step;
      bf16* dn = p ? dstA : dstB;
#pragma unroll
      for (int c = 0; c < 4; ++c) gload16(s2 + c * rstride, dn + c * 8 * 64);
    }

    const char* Kbase = (const char*)&KVs0[p][0];
    const char* Vbase = (const char*)&KVs1[p][0];

    // ---- QK^T + exp: P stays in registers as packed bf16x2 words ----
    int pw[4][2][2];                   // [nt][qt][word]
#pragma unroll
    for (int nt = 0; nt < 4; ++nt) {
      const char* rb = Kbase + (nt * 16 + l16) * 128;
      bf16x8 k0 = *(const bf16x8*)(rb + sw0);
      bf16x8 k1 = *(const bf16x8*)(rb + sw1);
#pragma unroll
      for (int qt = 0; qt < 2; ++qt) {
        f32x4 s = {};
        s = MFMA16(k0, qf[qt][0], s, 0, 0, 0);
        s = MFMA16(k1, qf[qt][1], s, 0, 0, 0);
        f32x4 pv;
#pragma unroll
        for (int e = 0; e < 4; ++e) pv[e] = __builtin_amdgcn_exp2f(s[e]);
        lac[qt] += pv;
        pw[nt][qt][0] = pk2(pv[0], pv[1]);
        pw[nt][qt][1] = pk2(pv[2], pv[3]);
      }
    }

    // ---- PV: 4-lane exchange builds B-fragments, then MFMA ----
#pragma unroll
    for (int ck = 0; ck < 2; ++ck) {
      union { bf16x8 v; int u[4]; } bp[2];
#pragma unroll
      for (int j = 0; j < 2; ++j) {
        int a0 = __shfl(pw[2 * ck][j][0], shA, 64);
        int b0 = __shfl(pw[2 * ck + 1][j][0], shA, 64);
        int a1 = __shfl(pw[2 * ck][j][1], shA, 64);
        int b1 = __shfl(pw[2 * ck + 1][j][1], shA, 64);
        int a2 = __shfl(pw[2 * ck][j][0], shB, 64);
        int b2 = __shfl(pw[2 * ck + 1][j][0], shB, 64);
        int a3 = __shfl(pw[2 * ck][j][1], shB, 64);
        int b3 = __shfl(pw[2 * ck + 1][j][1], shB, 64);
        bp[j].u[0] = hi ? b0 : a0;
        bp[j].u[1] = hi ? b1 : a1;
        bp[j].u[2] = hi ? b2 : a2;
        bp[j].u[3] = hi ? b3 : a3;
      }
      const int swc = ck ? sw1 : sw0;
#pragma unroll
      for (int dt = 0; dt < 4; ++dt) {
        bf16x8 av = *(const bf16x8*)(Vbase + (dt * 16 + l16) * 128 + swc);
        accO[dt][0] = MFMA16(av, bp[0].v, accO[dt][0], 0, 0, 0);
        accO[dt][1] = MFMA16(av, bp[1].v, accO[dt][1], 0, 0, 0);
      }
    }
  }

#pragma unroll
  for (int qt = 0; qt < 2; ++qt) {
    float lt = lac[qt][0] + lac[qt][1] + lac[qt][2] + lac[qt][3];
    lt += __shfl_xor(lt, 16);
    lt += __shfl_xor(lt, 32);
    if (lane < 16)
      lp[(size_t)(ks * 24 + bh) * SQQ + q0 + qt * 16 + l16] = lt;
#pragma unroll
    for (int dt = 0; dt < 4; ++dt) {
      bf16x4 ov;
#pragma unroll
      for (int r = 0; r < 4; ++r) ov[r] = (bf16)accO[dt][qt][r];
      *(bf16x4*)&Op[((size_t)(ks * 24 + bh) * SQQ + q0 + qt * 16 + l16) * HD + dt * 16 + quad * 4] = ov;
    }
  }
}

// -------------------------------------------------------------------------
// K4 (R12): fused merge+proj. Direct-fragment, barrier-free, LDS-free GEMM:
// out[4096 x 384] = merge(Opart,lp) @ Wpt + bias.
// Grid (64, 6), 128 thr = 2 waves; wave tile 32m x 64n; K fully unrolled.
// -------------------------------------------------------------------------
__global__ __launch_bounds__(128) void k_mproj(
    const bf16* __restrict__ Op, const float* __restrict__ lp,
    const bf16* __restrict__ Wt, const float* __restrict__ bias,
    float* __restrict__ out)
{
  const int tid = threadIdx.x;
  const int w = tid >> 6, lane = tid & 63, quad = lane >> 4, l16 = lane & 15;
  const int m0 = blockIdx.x * 64, n0 = blockIdx.y * 64;
  const int b = m0 >> 10;

  // inv[mt][h] = 1 / sum_sp l_part  for row q(mt), head h
  float inv[2][6];
#pragma unroll
  for (int mt = 0; mt < 2; ++mt) {
    const int q = (m0 & 1023) + w * 32 + mt * 16 + l16;
#pragma unroll
    for (int h = 0; h < 6; ++h) {
      float s = 0.f;
#pragma unroll
      for (int sp = 0; sp < 4; ++sp)
        s += lp[((size_t)(sp * 24 + b * NH + h) << 10) + q];
      inv[mt][h] = 1.0f / s;
    }
  }

  f32x4 acc[2][4] = {};
#pragma unroll
  for (int kc = 0; kc < 12; ++kc) {
    const int k0 = kc * 32;
    const int h = kc >> 1;                      // head is uniform per kc
    const int d0 = (k0 & 63) + quad * 8;        // within-head offset
    bf16x8 af[2];
#pragma unroll
    for (int mt = 0; mt < 2; ++mt) {
      const int q = (m0 & 1023) + w * 32 + mt * 16 + l16;
      const size_t off = ((size_t)(b * NH + h) << 16) + ((size_t)q << 6) + d0;
      bf16x8 v0 = *(const bf16x8*)&Op[off];
      bf16x8 v1 = *(const bf16x8*)&Op[off + ((size_t)24 << 16)];
      bf16x8 v2 = *(const bf16x8*)&Op[off + ((size_t)48 << 16)];
      bf16x8 v3 = *(const bf16x8*)&Op[off + ((size_t)72 << 16)];
      const float iv = inv[mt][h];
      bf16x8 m;
#pragma unroll
      for (int e = 0; e < 8; ++e)
        m[e] = (bf16)(((float)v0[e] + (float)v1[e] + (float)v2[e] + (float)v3[e]) * iv);
      af[mt] = m;
    }
    bf16x8 bw[4];
#pragma unroll
    for (int nt = 0; nt < 4; ++nt)
      bw[nt] = *(const bf16x8*)&Wt[(size_t)(n0 + nt * 16 + l16) * 384 + k0 + quad * 8];
#pragma unroll
    for (int mt = 0; mt < 2; ++mt)
#pragma unroll
      for (int nt = 0; nt < 4; ++nt)
        acc[mt][nt] = MFMA16(bw[nt], af[mt], acc[mt][nt], 0, 0, 0);
  }

  f32x4 bv[4];
#pragma unroll
  for (int nt = 0; nt < 4; ++nt)
    bv[nt] = *(const f32x4*)&bias[n0 + nt * 16 + quad * 4];
#pragma unroll
  for (int mt = 0; mt < 2; ++mt) {
    const int m = m0 + w * 32 + mt * 16 + l16;
#pragma unroll
    for (int nt = 0; nt < 4; ++nt) {
      f32x4 o = acc[mt][nt] + bv[nt];
      *(f32x4*)&out[(size_t)m * 384 + n0 + nt * 16 + quad * 4] = o;
    }
  }
}

// -------------------------------------------------------------------------
// ws layout (bytes):
//   Kb    @ 0         12582912   (qkv -> attn)
//   Vt    @ 12582912  12582912   (qkv -> attn)
//   Qp    @ 25165824   3145728   (qkv -> attn)
//   Wqt   @ 28311552    442368   (prep -> qkv)
//   Wpt   @ 28753920    294912   (prep -> mproj)
//   lp    @ 29048832    393216   (attn -> mproj)
//   Xb    @ 32587776   6291456   (prep -> qkv, dead after)
//   Opart @ 32587776  12582912   (attn -> mproj; overlays Xb)
// total 45170688
// -------------------------------------------------------------------------
extern "C" void kernel_launch(void* const* d_in, const int* in_sizes, int n_in,
                              void* d_out, int out_size, void* d_ws, size_t ws_size,
                              hipStream_t stream)
{
  (void)in_sizes; (void)n_in; (void)out_size; (void)ws_size;
  const float* X  = (const float*)d_in[0];
  const float* Wq = (const float*)d_in[1];
  const float* qb = (const float*)d_in[2];
  const float* Wp = (const float*)d_in[3];
  const float* pb = (const float*)d_in[4];
  float* out = (float*)d_out;

  char* ws = (char*)d_ws;
  bf16*  Kb    = (bf16*)(ws);
  bf16*  Vt    = (bf16*)(ws + 12582912);
  bf16*  Qp    = (bf16*)(ws + 25165824);
  bf16*  Wqt   = (bf16*)(ws + 28311552);
  bf16*  Wpt   = (bf16*)(ws + 28753920);
  float* lpart = (float*)(ws + 29048832);
  bf16*  Xb    = (bf16*)(ws + 32587776);
  bf16*  Opart = (bf16*)(ws + 32587776);   // overlays Xb (dead after k_qkv)

  k_prep <<<1896, 256, 0, stream>>>(X, Wq, Wp, Xb, Wqt, Wpt);
  k_qkv  <<<dim3(128, 9), 256, 0, stream>>>(Xb, Wqt, qb, Kb, Vt, Qp);
  k_attn <<<dim3(24, 8, 4), 256, 0, stream>>>(Qp, Kb, Vt, Opart, lpart);
  k_mproj<<<dim3(64, 6), 128, 0, stream>>>(Opart, lpart, Wpt, pb, out);
}

// Round 5
// 153.145 us; speedup vs baseline: 1.0465x; 1.0465x over previous
//
#include <hip/hip_runtime.h>

typedef __bf16 bf16;
typedef bf16 bf16x8 __attribute__((ext_vector_type(8)));
typedef bf16 bf16x4 __attribute__((ext_vector_type(4)));
typedef float f32x4 __attribute__((ext_vector_type(4)));

#define SEQ 4096
#define SQQ 1024
#define NH  6
#define HD  64

#define MFMA16 __builtin_amdgcn_mfma_f32_16x16x32_bf16

typedef const __attribute__((address_space(1))) void gvoid_t;
typedef __attribute__((address_space(3))) void svoid_t;

__device__ __forceinline__ void gload16(const bf16* g, bf16* l) {
  __builtin_amdgcn_global_load_lds((gvoid_t*)g, (svoid_t*)l, 16, 0, 0);
}

// -------------------------------------------------------------------------
// K0: prep (R11: LDS-tiled COALESCED transposes).
//   blocks [0,216):    Wq [192][1152] -> Wqt bf16 [1152][192], 32x32 tiles
//   blocks [216,360):  Wp [384][384]  -> Wpt bf16 [384][384],  32x32 tiles
//   blocks [360,1896): X f32 -> Xb bf16 (vec8, coalesced)
// -------------------------------------------------------------------------
__global__ __launch_bounds__(256) void k_prep(
    const float* __restrict__ X, const float* __restrict__ Wq,
    const float* __restrict__ Wp,
    bf16* __restrict__ Xb, bf16* __restrict__ Wqt, bf16* __restrict__ Wpt)
{
  const int bid = blockIdx.x, tid = threadIdx.x;
  if (bid < 360) {
    __shared__ float tile[32][33];
    const float* src; bf16* dst; int k0, n0, sld, dld;
    if (bid < 216) {                   // Wq: k-rows 192, n-cols 1152
      int bn = bid % 36, bk = bid / 36;
      n0 = bn * 32; k0 = bk * 32;
      src = Wq; dst = Wqt; sld = 1152; dld = 192;
    } else {                           // Wp: 384 x 384
      int j = bid - 216;
      int bn = j % 12, bk = j / 12;
      n0 = bn * 32; k0 = bk * 32;
      src = Wp; dst = Wpt; sld = 384; dld = 384;
    }
    int c = tid & 31, r4 = tid >> 5;   // load: coalesced along n
#pragma unroll
    for (int i = 0; i < 4; ++i)
      tile[r4 * 4 + i][c] = src[(size_t)(k0 + r4 * 4 + i) * sld + n0 + c];
    __syncthreads();
    int r = tid & 31, c4 = tid >> 5;   // store: coalesced along k
#pragma unroll
    for (int i = 0; i < 4; ++i)
      dst[(size_t)(n0 + c4 * 4 + i) * dld + k0 + r] = (bf16)tile[r][c4 * 4 + i];
  } else {
    int v = (bid - 360) * 256 + tid;   // 393216 vec8 chunks
    f32x4 x0 = *(const f32x4*)&X[(size_t)v * 8];
    f32x4 x1 = *(const f32x4*)&X[(size_t)v * 8 + 4];
    bf16x8 h;
#pragma unroll
    for (int e = 0; e < 4; ++e) { h[e] = (bf16)x0[e]; h[4 + e] = (bf16)x1[e]; }
    *(bf16x8*)&Xb[(size_t)v * 8] = h;
  }
}

// -------------------------------------------------------------------------
// K1: QKV GEMM — R13 (proven): cooperative LDS staging, global_load_lds
// double-buffered K-chunks, XOR pre-swizzled source + swizzled ds_read_b128.
// Qs (Q-pool buffer) overlays buf0 behind an extra barrier.
// -------------------------------------------------------------------------
__global__ __launch_bounds__(256) void k_qkv(
    const bf16* __restrict__ Xb, const bf16* __restrict__ Wt,
    const float* __restrict__ bias,
    bf16* __restrict__ Kb, bf16* __restrict__ Vt, bf16* __restrict__ Qp)
{
  // SB[buf][ A[128][64] | B[128][64] ]  = 2 x 32KB = 64KB
  __shared__ __attribute__((aligned(16))) bf16 SB[2][2 * 128 * 64];
  const int tid = threadIdx.x;
  const int w = tid >> 6, lane = tid & 63, quad = lane >> 4, l16 = lane & 15;
  const int wm = w & 1, wn = w >> 1;
  const int m0 = blockIdx.x * 128, n0 = blockIdx.y * 128;
  const int c3 = n0 / 384, nb = n0 - c3 * 384, b = m0 >> 12;

  const int sr = lane >> 3;            // 0..7  (row within 8-row stripe)
  const int sc = (lane & 7) ^ sr;      // pre-swizzled source granule

  // staging: waves 0,1 -> A rows [w*64, w*64+64); waves 2,3 -> B rows
  const bf16* gsrc;
  bf16* ldst;
  if (w < 2) {
    gsrc = Xb + (size_t)(m0 + w * 64 + sr) * 192 + sc * 8;
    ldst = &SB[0][w * 4096];
  } else {
    gsrc = Wt + (size_t)(n0 + (w - 2) * 64 + sr) * 192 + sc * 8;
    ldst = &SB[0][8192 + (w - 2) * 4096];
  }
  const int bufstep = 2 * 128 * 64;    // elems between buffers

  // prologue: stage chunk 0 into buf 0 (8 issues/wave, 16B each)
#pragma unroll
  for (int i = 0; i < 8; ++i)
    gload16(gsrc + i * 1536, ldst + i * 512);

  // swizzled read offsets (bytes within a 128B row)
  const int sw0 = ((quad ^ (l16 & 7)) * 16);
  const int sw1 = (((4 + quad) ^ (l16 & 7)) * 16);

  f32x4 acc[4][4] = {};

  for (int kc = 0; kc < 3; ++kc) {
    const int p = kc & 1;
    __asm__ volatile("s_waitcnt vmcnt(0)" ::: "memory");
    __syncthreads();
    if (kc < 2) {
      const bf16* g2 = gsrc + (kc + 1) * 64;
      bf16* d2 = ldst + (p ^ 1) * bufstep;
#pragma unroll
      for (int i = 0; i < 8; ++i)
        gload16(g2 + i * 1536, d2 + i * 512);
    }
    const char* Ab = (const char*)&SB[p][0];
    const char* Bb = (const char*)&SB[p][8192];
#pragma unroll
    for (int kk = 0; kk < 2; ++kk) {
      const int swo = kk ? sw1 : sw0;
      bf16x8 af[4], bw[4];
#pragma unroll
      for (int t = 0; t < 4; ++t) {
        af[t] = *(const bf16x8*)(Ab + (wm * 64 + t * 16 + l16) * 128 + swo);
        bw[t] = *(const bf16x8*)(Bb + (wn * 64 + t * 16 + l16) * 128 + swo);
      }
      if (c3 == 2) {
#pragma unroll
        for (int mt = 0; mt < 4; ++mt)
#pragma unroll
          for (int nt = 0; nt < 4; ++nt)
            acc[mt][nt] = MFMA16(af[mt], bw[nt], acc[mt][nt], 0, 0, 0);
      } else {
#pragma unroll
        for (int mt = 0; mt < 4; ++mt)
#pragma unroll
          for (int nt = 0; nt < 4; ++nt)
            acc[mt][nt] = MFMA16(bw[nt], af[mt], acc[mt][nt], 0, 0, 0);
      }
    }
  }

  if (c3 == 2) {
    float bn[4];
#pragma unroll
    for (int nt = 0; nt < 4; ++nt) bn[nt] = bias[n0 + wn * 64 + nt * 16 + l16];
#pragma unroll
    for (int mt = 0; mt < 4; ++mt) {
      int sb = (m0 & 4095) + wm * 64 + mt * 16 + quad * 4;
#pragma unroll
      for (int nt = 0; nt < 4; ++nt) {
        int dcol = nb + wn * 64 + nt * 16 + l16;
        int h = dcol >> 6, dd = dcol & 63;
        bf16x4 pv;
#pragma unroll
        for (int r = 0; r < 4; ++r) pv[r] = (bf16)(acc[mt][nt][r] + bn[nt]);
        *(bf16x4*)&Vt[((size_t)(b * NH + h) * HD + dd) * SEQ + sb] = pv;
      }
    }
  } else if (c3 == 1) {
    f32x4 bv[4];
#pragma unroll
    for (int nt = 0; nt < 4; ++nt)
      bv[nt] = *(const f32x4*)&bias[n0 + wn * 64 + nt * 16 + quad * 4];
#pragma unroll
    for (int mt = 0; mt < 4; ++mt) {
      int s = (m0 & 4095) + wm * 64 + mt * 16 + l16;
#pragma unroll
      for (int nt = 0; nt < 4; ++nt) {
        int ncol = nb + wn * 64 + nt * 16 + quad * 4;
        int h = ncol >> 6, dd = ncol & 63;
        bf16x4 pv;
#pragma unroll
        for (int r = 0; r < 4; ++r) pv[r] = (bf16)(acc[mt][nt][r] + bv[nt][r]);
        *(bf16x4*)&Kb[((size_t)(b * NH + h) * SEQ + s) * HD + dd] = pv;
      }
    }
  } else {
    bf16* Qs = &SB[0][0];              // overlay (17408 elems <= 32768)
    f32x4 bv[4];
#pragma unroll
    for (int nt = 0; nt < 4; ++nt)
      bv[nt] = *(const f32x4*)&bias[n0 + wn * 64 + nt * 16 + quad * 4];
    __syncthreads();                   // buf0 was read by the kc=2 compute
#pragma unroll
    for (int mt = 0; mt < 4; ++mt) {
      int ml = wm * 64 + mt * 16 + l16;
#pragma unroll
      for (int nt = 0; nt < 4; ++nt) {
        int ncl = wn * 64 + nt * 16 + quad * 4;
        bf16x4 pv;
#pragma unroll
        for (int r = 0; r < 4; ++r) pv[r] = (bf16)(acc[mt][nt][r] + bv[nt][r]);
        *(bf16x4*)&Qs[ml * 136 + ncl] = pv;
      }
    }
    __syncthreads();
    const int wq = tid >> 3, cg = tid & 7;
    const int hq = (m0 & 4095) >> 7;
#pragma unroll
    for (int j8 = 0; j8 < 2; ++j8) {
      int co = cg * 16 + j8 * 8;
      bf16x8 q0 = *(const bf16x8*)&Qs[(2 * wq)     * 136 + co];
      bf16x8 q1 = *(const bf16x8*)&Qs[(2 * wq + 1) * 136 + co];
      bf16x8 q2 = *(const bf16x8*)&Qs[(64 + 2 * wq)     * 136 + co];
      bf16x8 q3 = *(const bf16x8*)&Qs[(64 + 2 * wq + 1) * 136 + co];
      bf16x8 o;
#pragma unroll
      for (int e = 0; e < 8; ++e) {
        float mx = fmaxf(fmaxf((float)q0[e], (float)q1[e]),
                         fmaxf((float)q2[e], (float)q3[e]));
        o[e] = (bf16)(mx * 0.180336880111f);   // 0.125 * log2(e)
      }
      int gc = nb + co;
      int h = gc >> 6, d0 = gc & 63;
      *(bf16x8*)&Qp[((size_t)(b * NH + h) * SQQ + hq * 32 + wq) * HD + d0] = o;
    }
  }
}

// -------------------------------------------------------------------------
// K3: attention — R6-EXACT (restored; proven 42.4-42.6 us on two containers;
// R14 swizzle+setprio and R15 shfl-exchange both regressed it).
// 4 waves/block, 32 q/wave, double-buffered KV LDS via global_load_lds,
// XOR-swizzled conflict-free reads, S^T=K.Q^T, no max-stabilization,
// K-split 4. Grid (24, 8, 4), 256 thr.
// -------------------------------------------------------------------------
__global__ __launch_bounds__(256) void k_attn(
    const bf16* __restrict__ Qp, const bf16* __restrict__ Kb,
    const bf16* __restrict__ Vt, bf16* __restrict__ Op, float* __restrict__ lp)
{
  __shared__ __attribute__((aligned(16))) bf16 KVs0[2][64 * 64];  // K [kpos][d^]
  __shared__ __attribute__((aligned(16))) bf16 KVs1[2][64 * 64];  // V^T [d][kpos^]
  __shared__ __attribute__((aligned(16))) bf16 Pq[4][32 * 72];    // per-wave P

  const int tid = threadIdx.x;
  const int w = tid >> 6, lane = tid & 63, quad = lane >> 4, l16 = lane & 15;
  const int bh = blockIdx.x, qb = blockIdx.y, ks = blockIdx.z;
  const int q0 = qb * 128 + w * 32;

  const bf16* Qg = Qp + (size_t)bh * SQQ * HD;
  const bf16* Kg = Kb + (size_t)bh * SEQ * HD;
  const bf16* Vg = Vt + (size_t)bh * HD * SEQ;

  bf16x8 qf[2][2];
#pragma unroll
  for (int qt = 0; qt < 2; ++qt)
#pragma unroll
    for (int dk = 0; dk < 2; ++dk)
      qf[qt][dk] = *(const bf16x8*)&Qg[(size_t)(q0 + qt * 16 + l16) * HD + dk * 32 + quad * 8];

  const int swz = l16 & 7;
  const int sw0 = ((quad ^ swz) * 16);
  const int sw1 = (((quad + 4) ^ swz) * 16);
  const int sr = lane >> 3;          // 0..7
  const int sc = (lane & 7) ^ sr;    // XOR-permuted source chunk

  const bf16* src;
  bf16 *dstA, *dstB;
  size_t rstride, step;
  if (w < 2) {
    src = Kg + (size_t)(ks * 1024 + w * 32 + sr) * HD + sc * 8;
    dstA = &KVs0[0][(w * 32) * 64];
    dstB = &KVs0[1][(w * 32) * 64];
    rstride = 8 * HD;  step = 64 * HD;
  } else {
    src = Vg + (size_t)((w - 2) * 32 + sr) * SEQ + ks * 1024 + sc * 8;
    dstA = &KVs1[0][((w - 2) * 32) * 64];
    dstB = &KVs1[1][((w - 2) * 32) * 64];
    rstride = 8 * SEQ; step = 64;
  }

#pragma unroll
  for (int c = 0; c < 4; ++c) gload16(src + c * rstride, dstA + c * 8 * 64);

  f32x4 lac[2] = {};
  f32x4 accO[4][2] = {};
  bf16* PqW = &Pq[w][0];

  for (int it = 0; it < 16; ++it) {
    const int p = it & 1;
    __asm__ volatile("s_waitcnt vmcnt(0)" ::: "memory");
    __syncthreads();
    if (it < 15) {
      const bf16* s2 = src + (size_t)(it + 1) * step;
      bf16* dn = p ? dstA : dstB;
#pragma unroll
      for (int c = 0; c < 4; ++c) gload16(s2 + c * rstride, dn + c * 8 * 64);
    }

    const char* Kbase = (const char*)&KVs0[p][0];
    const char* Vbase = (const char*)&KVs1[p][0];

#pragma unroll
    for (int nt = 0; nt < 4; ++nt) {
      const char* rb = Kbase + (nt * 16 + l16) * 128;
      bf16x8 k0 = *(const bf16x8*)(rb + sw0);
      bf16x8 k1 = *(const bf16x8*)(rb + sw1);
#pragma unroll
      for (int qt = 0; qt < 2; ++qt) {
        f32x4 s = {};
        s = MFMA16(k0, qf[qt][0], s, 0, 0, 0);
        s = MFMA16(k1, qf[qt][1], s, 0, 0, 0);
        f32x4 pv;
#pragma unroll
        for (int e = 0; e < 4; ++e) pv[e] = __builtin_amdgcn_exp2f(s[e]);
        lac[qt] += pv;
        bf16x4 pb4;
#pragma unroll
        for (int e = 0; e < 4; ++e) pb4[e] = (bf16)pv[e];
        *(bf16x4*)&PqW[(qt * 16 + l16) * 72 + nt * 16 + quad * 4] = pb4;
      }
    }
    __asm__ volatile("s_waitcnt lgkmcnt(0)" ::: "memory");

#pragma unroll
    for (int ck = 0; ck < 2; ++ck) {
      bf16x8 bp0 = *(const bf16x8*)&PqW[(l16) * 72 + ck * 32 + quad * 8];
      bf16x8 bp1 = *(const bf16x8*)&PqW[(16 + l16) * 72 + ck * 32 + quad * 8];
      const int swc = ck ? sw1 : sw0;
#pragma unroll
      for (int dt = 0; dt < 4; ++dt) {
        bf16x8 av = *(const bf16x8*)(Vbase + (dt * 16 + l16) * 128 + swc);
        accO[dt][0] = MFMA16(av, bp0, accO[dt][0], 0, 0, 0);
        accO[dt][1] = MFMA16(av, bp1, accO[dt][1], 0, 0, 0);
      }
    }
  }

#pragma unroll
  for (int qt = 0; qt < 2; ++qt) {
    float lt = lac[qt][0] + lac[qt][1] + lac[qt][2] + lac[qt][3];
    lt += __shfl_xor(lt, 16);
    lt += __shfl_xor(lt, 32);
    if (lane < 16)
      lp[(size_t)(ks * 24 + bh) * SQQ + q0 + qt * 16 + l16] = lt;
#pragma unroll
    for (int dt = 0; dt < 4; ++dt) {
      bf16x4 ov;
#pragma unroll
      for (int r = 0; r < 4; ++r) ov[r] = (bf16)accO[dt][qt][r];
      *(bf16x4*)&Op[((size_t)(ks * 24 + bh) * SQQ + q0 + qt * 16 + l16) * HD + dt * 16 + quad * 4] = ov;
    }
  }
}

// -------------------------------------------------------------------------
// K4 (R16): fused merge+proj, now 4 waves/block (was 2). R12's lesson
// applied to itself: at 2 waves x 384 blocks = 3 waves/CU the direct-
// fragment loads hit the Little's-law latency wall (same mechanism that
// made R12-qkv 50us). 4 waves of 16 m-rows each double waves/CU (6) and
// in-flight bytes; W re-read 2x per block is L2-cheap (+18MB).
// Math unchanged: sum 4 bf16 partials in f32, scale by inv softmax-denom,
// round to bf16, MFMA against Wpt. Grid (64, 6), 256 thr.
// -------------------------------------------------------------------------
__global__ __launch_bounds__(256) void k_mproj(
    const bf16* __restrict__ Op, const float* __restrict__ lp,
    const bf16* __restrict__ Wt, const float* __restrict__ bias,
    float* __restrict__ out)
{
  const int tid = threadIdx.x;
  const int w = tid >> 6, lane = tid & 63, quad = lane >> 4, l16 = lane & 15;
  const int m0 = blockIdx.x * 64, n0 = blockIdx.y * 64;
  const int b = m0 >> 10;
  const int q = (m0 & 1023) + w * 16 + l16;     // this lane's q-row

  // inv[h] = 1 / sum_sp l_part  for row q, head h
  float inv[6];
#pragma unroll
  for (int h = 0; h < 6; ++h) {
    float s = 0.f;
#pragma unroll
    for (int sp = 0; sp < 4; ++sp)
      s += lp[((size_t)(sp * 24 + b * NH + h) << 10) + q];
    inv[h] = 1.0f / s;
  }

  f32x4 acc[4] = {};
#pragma unroll
  for (int kc = 0; kc < 12; ++kc) {
    const int k0 = kc * 32;
    const int h = kc >> 1;                      // head is uniform per kc
    const int d0 = (k0 & 63) + quad * 8;        // within-head offset
    const size_t off = ((size_t)(b * NH + h) << 16) + ((size_t)q << 6) + d0;
    bf16x8 v0 = *(const bf16x8*)&Op[off];
    bf16x8 v1 = *(const bf16x8*)&Op[off + ((size_t)24 << 16)];
    bf16x8 v2 = *(const bf16x8*)&Op[off + ((size_t)48 << 16)];
    bf16x8 v3 = *(const bf16x8*)&Op[off + ((size_t)72 << 16)];
    const float iv = inv[h];
    bf16x8 af;
#pragma unroll
    for (int e = 0; e < 8; ++e)
      af[e] = (bf16)(((float)v0[e] + (float)v1[e] + (float)v2[e] + (float)v3[e]) * iv);
    bf16x8 bw[4];
#pragma unroll
    for (int nt = 0; nt < 4; ++nt)
      bw[nt] = *(const bf16x8*)&Wt[(size_t)(n0 + nt * 16 + l16) * 384 + k0 + quad * 8];
#pragma unroll
    for (int nt = 0; nt < 4; ++nt)
      acc[nt] = MFMA16(bw[nt], af, acc[nt], 0, 0, 0);
  }

  f32x4 bv[4];
#pragma unroll
  for (int nt = 0; nt < 4; ++nt)
    bv[nt] = *(const f32x4*)&bias[n0 + nt * 16 + quad * 4];
  const int m = m0 + w * 16 + l16;
#pragma unroll
  for (int nt = 0; nt < 4; ++nt) {
    f32x4 o = acc[nt] + bv[nt];
    *(f32x4*)&out[(size_t)m * 384 + n0 + nt * 16 + quad * 4] = o;
  }
}

// -------------------------------------------------------------------------
// ws layout (bytes):
//   Kb    @ 0         12582912   (qkv -> attn)
//   Vt    @ 12582912  12582912   (qkv -> attn)
//   Qp    @ 25165824   3145728   (qkv -> attn)
//   Wqt   @ 28311552    442368   (prep -> qkv)
//   Wpt   @ 28753920    294912   (prep -> mproj)
//   lp    @ 29048832    393216   (attn -> mproj)
//   Xb    @ 32587776   6291456   (prep -> qkv, dead after)
//   Opart @ 32587776  12582912   (attn -> mproj; overlays Xb)
// total 45170688
// -------------------------------------------------------------------------
extern "C" void kernel_launch(void* const* d_in, const int* in_sizes, int n_in,
                              void* d_out, int out_size, void* d_ws, size_t ws_size,
                              hipStream_t stream)
{
  (void)in_sizes; (void)n_in; (void)out_size; (void)ws_size;
  const float* X  = (const float*)d_in[0];
  const float* Wq = (const float*)d_in[1];
  const float* qb = (const float*)d_in[2];
  const float* Wp = (const float*)d_in[3];
  const float* pb = (const float*)d_in[4];
  float* out = (float*)d_out;

  char* ws = (char*)d_ws;
  bf16*  Kb    = (bf16*)(ws);
  bf16*  Vt    = (bf16*)(ws + 12582912);
  bf16*  Qp    = (bf16*)(ws + 25165824);
  bf16*  Wqt   = (bf16*)(ws + 28311552);
  bf16*  Wpt   = (bf16*)(ws + 28753920);
  float* lpart = (float*)(ws + 29048832);
  bf16*  Xb    = (bf16*)(ws + 32587776);
  bf16*  Opart = (bf16*)(ws + 32587776);   // overlays Xb (dead after k_qkv)

  k_prep <<<1896, 256, 0, stream>>>(X, Wq, Wp, Xb, Wqt, Wpt);
  k_qkv  <<<dim3(128, 9), 256, 0, stream>>>(Xb, Wqt, qb, Kb, Vt, Qp);
  k_attn <<<dim3(24, 8, 4), 256, 0, stream>>>(Qp, Kb, Vt, Opart, lpart);
  k_mproj<<<dim3(64, 6), 256, 0, stream>>>(Opart, lpart, Wpt, pb, out);
}